// Round 7
// baseline (223.835 us; speedup 1.0000x reference)
//
#include <hip/hip_runtime.h>
#include <math.h>

#define NB 8
#define NA 32
#define NCELL 256
#define NPAIR 496
#define SLOT 496          // max triplets per cell
#define FST 10            // 9 features + weight
#define TC 32             // triplets per chunk (8 per thread-lane-group)
#define XS 36             // padded activation row stride (floats, 16B-aligned)
#define NQ 4              // chunk-slots per cell
#define CUTOFF_F 3.5f
#define EPS_F 1e-7f
#define CLIP_MIN_F 1e-10f
#define PI_F 3.14159274101257324f   // float32(np.pi)

// ---------------- K1: compact active triplets, compute features ----------------
__global__ __launch_bounds__(256) void aev_feat(
    const float* __restrict__ D, const float* __restrict__ S,
    float* __restrict__ feat, int* __restrict__ count, float* __restrict__ GA)
{
    __shared__ float Dm[NA][NA];
    __shared__ float Sv[NA];
    __shared__ int s_T;
    const int tid = threadIdx.x;
    const int cell = blockIdx.x;
    const int b = cell >> 5, i = cell & 31;

    for (int idx = tid; idx < NA * NA; idx += 256)
        ((float*)Dm)[idx] = D[b * NA * NA + idx];
    if (tid < NA) Sv[tid] = S[b * NA + tid];
    if (tid == 0) s_T = 0;
    GA[cell * 256 + tid] = 0.f;
    __syncthreads();

    for (int p = tid; p < NPAIR; p += 256) {
        int rem = p, j = 0;
        while (rem >= 31 - j) { rem -= 31 - j; ++j; }
        const int k = j + 1 + rem;
        const float dij = Dm[i][j], dik = Dm[i][k];
        if (dij < CUTOFF_F && dij != 0.f && dik < CUTOFF_F && dik != 0.f) {
            const int slot = atomicAdd(&s_T, 1);
            const float Rij = dij, Rik = dik, Rjk = Dm[j][k];
            const float zi = Sv[i], zj = Sv[j], zk = Sv[k];
            const float ci = (Rij*Rij + Rik*Rik - Rjk*Rjk) / fmaxf(2.f*Rij*Rik, CLIP_MIN_F);
            const float cj = (Rij*Rij + Rjk*Rjk - Rik*Rik) / fmaxf(2.f*Rij*Rjk, CLIP_MIN_F);
            const float ck = (Rik*Rik + Rjk*Rjk - Rij*Rij) / fmaxf(2.f*Rik*Rjk, CLIP_MIN_F);
            float g0 = Rij + Rik + Rjk;
            float g1 = Rij*Rik + Rij*Rjk + Rik*Rjk;
            float g2 = Rij*Rik*Rjk;
            const float gn = sqrtf(g0*g0 + g1*g1 + g2*g2) + EPS_F;
            float h0 = zi + zj + zk;
            float h1 = ci + cj + ck;
            float h2 = zi*(zj + zk) + zj*zk - ci*(cj + ck) - cj*ck;
            float h3 = zi*(cj + ck) + ci*(zj + zk) + zj*ck + cj*zk;
            float h4 = zi*(zj*zk - cj*ck) - ci*(zj*ck + cj*zk);
            float h5 = zi*(zj*ck + cj*zk) + ci*(zj*zk - cj*ck);
            const float hn = sqrtf(h0*h0 + h1*h1 + h2*h2 + h3*h3 + h4*h4 + h5*h5) + EPS_F;
            const float fcij = 0.5f * cosf(PI_F * Rij / CUTOFF_F) + 0.5f;
            const float fcik = 0.5f * cosf(PI_F * Rik / CUTOFF_F) + 0.5f;
            float* fp = &feat[(cell * SLOT + slot) * FST];
            fp[0] = g0 / gn; fp[1] = g1 / gn; fp[2] = g2 / gn;
            fp[3] = h0 / hn; fp[4] = h1 / hn; fp[5] = h2 / hn;
            fp[6] = h3 / hn; fp[7] = h4 / hn; fp[8] = h5 / hn;
            fp[9] = fcij * fcik;
        }
    }
    __syncthreads();
    if (tid == 0) count[cell] = s_T;
}

// -------- async global->LDS staging (no VGPR payload) --------
__device__ __forceinline__ void cp_async16(const float* g, float* l) {
    __builtin_amdgcn_global_load_lds(
        (const __attribute__((address_space(1))) unsigned int*)g,
        (__attribute__((address_space(3))) unsigned int*)l, 16, 0, 0);
}

// stage one 4096-float (16KB) slice: 4 waves x 4 issues x (64 lanes x 16B)
__device__ __forceinline__ void stage16k(const float* __restrict__ g,
                                         float* __restrict__ buf, int tid) {
    const int lane = tid & 63, w = tid >> 6;
#pragma unroll
    for (int r = 0; r < 4; ++r) {
        const int off = (w * 4 + r) * 256;
        cp_async16(g + off + lane * 4, buf + off);   // LDS base wave-uniform
    }
}

// -------- layer computes (weights + bias from LDS) --------
// 64-out layer: thread = 1 feature x 8 triplets (2x float4). BOUNDED unroll —
// full unroll lets the scheduler hoist all ds_reads and blow VGPRs (r4/r5 bug).
template<int K, bool RES>
__device__ __forceinline__ void compute64(
    const float* __restrict__ Wl, const float* __restrict__ bl,
    const float* __restrict__ X, float* __restrict__ Y,
    const float* __restrict__ R, int tid)
{
    const int fi = tid & 63;
    const int xo = (tid >> 6) * 8;       // wave-uniform -> broadcast reads
    const float bb = bl[fi];
    float a[8];
#pragma unroll
    for (int r = 0; r < 8; ++r) a[r] = bb;
#pragma unroll 4
    for (int k = 0; k < K; ++k) {
        const float4 x0 = *(const float4*)&X[k * XS + xo];
        const float4 x1 = *(const float4*)&X[k * XS + xo + 4];
        const float w = Wl[k * 64 + fi];
        a[0] += x0.x * w; a[1] += x0.y * w; a[2] += x0.z * w; a[3] += x0.w * w;
        a[4] += x1.x * w; a[5] += x1.y * w; a[6] += x1.z * w; a[7] += x1.w * w;
    }
    float4 y0, y1;
    y0.x = tanhf(a[0]); y0.y = tanhf(a[1]); y0.z = tanhf(a[2]); y0.w = tanhf(a[3]);
    y1.x = tanhf(a[4]); y1.y = tanhf(a[5]); y1.z = tanhf(a[6]); y1.w = tanhf(a[7]);
    if (RES) {
        const float4 r0 = *(const float4*)&R[fi * XS + xo];
        const float4 r1 = *(const float4*)&R[fi * XS + xo + 4];
        y0.x += r0.x; y0.y += r0.y; y0.z += r0.z; y0.w += r0.w;
        y1.x += r1.x; y1.y += r1.y; y1.z += r1.z; y1.w += r1.w;
    }
    *(float4*)&Y[fi * XS + xo]     = y0;
    *(float4*)&Y[fi * XS + xo + 4] = y1;
}

// 64->128 layer, one 32-row k-slice. Thread = outputs (fo, fo+64) x 8 triplets.
__device__ __forceinline__ void compute5_part(
    const float* __restrict__ Wl /*32 rows x 128*/, const float* __restrict__ X,
    int k0, float (&a0)[8], float (&a1)[8], int tid)
{
    const int fo = tid & 63;
    const int xo = (tid >> 6) * 8;
#pragma unroll 2
    for (int k = 0; k < 32; ++k) {
        const float4 x0 = *(const float4*)&X[(k0 + k) * XS + xo];
        const float4 x1 = *(const float4*)&X[(k0 + k) * XS + xo + 4];
        const float w0 = Wl[k * 128 + fo];
        const float w1 = Wl[k * 128 + fo + 64];
        a0[0] += x0.x * w0; a0[1] += x0.y * w0; a0[2] += x0.z * w0; a0[3] += x0.w * w0;
        a0[4] += x1.x * w0; a0[5] += x1.y * w0; a0[6] += x1.z * w0; a0[7] += x1.w * w0;
        a1[0] += x0.x * w1; a1[1] += x0.y * w1; a1[2] += x0.z * w1; a1[3] += x0.w * w1;
        a1[4] += x1.x * w1; a1[5] += x1.y * w1; a1[6] += x1.z * w1; a1[7] += x1.w * w1;
    }
}

// 128->256 layer, one 16-row k-slice. Thread = 2 features x 16 triplets.
__device__ __forceinline__ void compute6_part(
    const float* __restrict__ Wl /*16 rows x 256*/, const float* __restrict__ X,
    int fo, int to, float (&a0)[16], float (&a1)[16])
{
#pragma unroll 2
    for (int k = 0; k < 16; ++k) {
        const float2 wv = *(const float2*)&Wl[k * 256 + fo];
        const float4 x0 = *(const float4*)&X[k * XS + to];
        const float4 x1 = *(const float4*)&X[k * XS + to + 4];
        const float4 x2 = *(const float4*)&X[k * XS + to + 8];
        const float4 x3 = *(const float4*)&X[k * XS + to + 12];
        a0[0]  += x0.x * wv.x; a0[1]  += x0.y * wv.x; a0[2]  += x0.z * wv.x; a0[3]  += x0.w * wv.x;
        a0[4]  += x1.x * wv.x; a0[5]  += x1.y * wv.x; a0[6]  += x1.z * wv.x; a0[7]  += x1.w * wv.x;
        a0[8]  += x2.x * wv.x; a0[9]  += x2.y * wv.x; a0[10] += x2.z * wv.x; a0[11] += x2.w * wv.x;
        a0[12] += x3.x * wv.x; a0[13] += x3.y * wv.x; a0[14] += x3.z * wv.x; a0[15] += x3.w * wv.x;
        a1[0]  += x0.x * wv.y; a1[1]  += x0.y * wv.y; a1[2]  += x0.z * wv.y; a1[3]  += x0.w * wv.y;
        a1[4]  += x1.x * wv.y; a1[5]  += x1.y * wv.y; a1[6]  += x1.z * wv.y; a1[7]  += x1.w * wv.y;
        a1[8]  += x2.x * wv.y; a1[9]  += x2.y * wv.y; a1[10] += x2.z * wv.y; a1[11] += x2.w * wv.y;
        a1[12] += x3.x * wv.y; a1[13] += x3.y * wv.y; a1[14] += x3.z * wv.y; a1[15] += x3.w * wv.y;
    }
}

// ---------------- K2: async-pipelined MLP (3-buffer rotation, TC=32) ---------
// Phase i consumes slice s_i from buf[i%3], issues s_{i+2} into buf[(i+2)%3]
// (whose content was consumed at phase i-1, one barrier back).
__global__ __launch_bounds__(256) void aev_mlp(
    const float* __restrict__ feat, const int* __restrict__ count,
    const float* __restrict__ W0, const float* __restrict__ b0,
    const float* __restrict__ W1, const float* __restrict__ b1,
    const float* __restrict__ W2, const float* __restrict__ b2,
    const float* __restrict__ W3, const float* __restrict__ b3,
    const float* __restrict__ W4, const float* __restrict__ b4,
    const float* __restrict__ W5, const float* __restrict__ b5,
    const float* __restrict__ W6, const float* __restrict__ b6,
    float* __restrict__ GA)
{
    __shared__ __align__(16) float WB0[4096];
    __shared__ __align__(16) float WB1[4096];
    __shared__ __align__(16) float WB2[4096];
    __shared__ __align__(16) float Xs[9 * XS];
    __shared__ __align__(16) float U0[64 * XS];
    __shared__ __align__(16) float U1[64 * XS];
    __shared__ __align__(16) float U2[64 * XS];
    __shared__ __align__(16) float U3[128 * XS];
    __shared__ float wsh[TC];
    __shared__ float bsh[704];   // b0..b4 @0..319, b5 @320, b6 @448

    const int tid = threadIdx.x;
    // cell*NQ+q mapping: sibling chunk-blocks of one cell dispatch to
    // DIFFERENT CUs (q-major would stack them on one CU and serialize —
    // only 1 block/CU fits at this LDS size).
    const int cell = blockIdx.x >> 2;
    const int q = blockIdx.x & 3;
    const int T = count[cell];
    const int nch = (T + TC - 1) / TC;
    if (q >= nch) return;        // block-uniform exit (no barriers yet)

    if (tid < 64) {
        bsh[tid]       = b0[tid];
        bsh[64 + tid]  = b1[tid];
        bsh[128 + tid] = b2[tid];
        bsh[192 + tid] = b3[tid];
        bsh[256 + tid] = b4[tid];
    }
    if (tid < 128) bsh[320 + tid] = b5[tid];
    bsh[448 + tid] = b6[tid];

    const int fo6 = (tid & 127) * 2;     // L6 output pair
    const int to6 = (tid >> 7) * 16;     // L6 triplet half (wave-uniform)
    float gacc0 = 0.f, gacc1 = 0.f;

    for (int c = q; c < nch; c += NQ) {
        const int t0 = c * TC;

        // ---- prologue: issue W1->WB1; W0->WB0 (sync, 2.3KB); features ----
        stage16k(W1, WB1, tid);
        if (tid < 144) ((float4*)WB0)[tid] = ((const float4*)W0)[tid];
        for (int idx = tid; idx < TC * FST; idx += 256) {
            const int t = idx / FST, qf = idx % FST;
            const int slot = t0 + t;
            const float v = (slot < T) ? feat[(cell * SLOT + t0) * FST + idx] : 0.f;
            if (qf == 9) wsh[t] = v; else Xs[qf * XS + t] = v;
        }
        __syncthreads();

        // ph0: L0 (WB0); issue W2->WB2
        stage16k(W2, WB2, tid);
        compute64<9,  false>(WB0, bsh + 0,   Xs, U0, nullptr, tid);  // x_res -> U0
        __syncthreads();
        // ph1: L1 (WB1, res U0); issue W3->WB0
        stage16k(W3, WB0, tid);
        compute64<64, true >(WB1, bsh + 64,  U0, U1, U0, tid);       // xb1 -> U1
        __syncthreads();
        // ph2: L2 (WB2); issue W4->WB1
        stage16k(W4, WB1, tid);
        compute64<64, false>(WB2, bsh + 128, U1, U2, nullptr, tid);  // x2 -> U2
        __syncthreads();
        // ph3: L3 (WB0); issue W5a->WB2
        stage16k(W5, WB2, tid);
        compute64<64, false>(WB0, bsh + 192, U2, U0, nullptr, tid);  // x3 -> U0
        __syncthreads();
        // ph4: L4 (WB1, res U1); issue W5b->WB0
        stage16k(W5 + 4096, WB0, tid);
        compute64<64, true >(WB1, bsh + 256, U0, U2, U1, tid);       // xb2 -> U2
        __syncthreads();

        // ---- L5: 2 k-slices, persistent accumulators ----
        float a0[8], a1[8];
        {
            const int fo = tid & 63;
            const float bb0 = bsh[320 + fo], bb1 = bsh[320 + fo + 64];
#pragma unroll
            for (int r = 0; r < 8; ++r) { a0[r] = bb0; a1[r] = bb1; }
        }
        // ph5: L5a (WB2); issue W6 s0->WB1
        stage16k(W6, WB1, tid);
        compute5_part(WB2, U2, 0, a0, a1, tid);
        __syncthreads();
        // ph6: L5b (WB0), tanh -> U3; issue W6 s1->WB2
        stage16k(W6 + 4096, WB2, tid);
        compute5_part(WB0, U2, 32, a0, a1, tid);
        {
            const int fo = tid & 63;
            const int xo = (tid >> 6) * 8;
            float4 y0, y1;
            y0.x = tanhf(a0[0]); y0.y = tanhf(a0[1]); y0.z = tanhf(a0[2]); y0.w = tanhf(a0[3]);
            y1.x = tanhf(a0[4]); y1.y = tanhf(a0[5]); y1.z = tanhf(a0[6]); y1.w = tanhf(a0[7]);
            *(float4*)&U3[fo * XS + xo]     = y0;
            *(float4*)&U3[fo * XS + xo + 4] = y1;
            y0.x = tanhf(a1[0]); y0.y = tanhf(a1[1]); y0.z = tanhf(a1[2]); y0.w = tanhf(a1[3]);
            y1.x = tanhf(a1[4]); y1.y = tanhf(a1[5]); y1.z = tanhf(a1[6]); y1.w = tanhf(a1[7]);
            *(float4*)&U3[(fo + 64) * XS + xo]     = y0;
            *(float4*)&U3[(fo + 64) * XS + xo + 4] = y1;
        }
        __syncthreads();

        // ---- L6: 8 k-slices of 16 rows; thread = 2 outputs x 16 triplets ----
        float c0[16], c1[16];
        {
            const float bb0 = bsh[448 + fo6], bb1 = bsh[448 + fo6 + 1];
#pragma unroll
            for (int r = 0; r < 16; ++r) { c0[r] = bb0; c1[r] = bb1; }
        }
        // ph7: s0 (WB1); issue s2->WB0
        stage16k(W6 + 2 * 4096, WB0, tid);
        compute6_part(WB1, U3 + 0 * XS * 16 + 0, fo6, to6, c0, c1);
        __syncthreads();
        // ph8: s1 (WB2); issue s3->WB1
        stage16k(W6 + 3 * 4096, WB1, tid);
        compute6_part(WB2, U3 + 16 * XS, fo6, to6, c0, c1);
        __syncthreads();
        // ph9: s2 (WB0); issue s4->WB2
        stage16k(W6 + 4 * 4096, WB2, tid);
        compute6_part(WB0, U3 + 32 * XS, fo6, to6, c0, c1);
        __syncthreads();
        // ph10: s3 (WB1); issue s5->WB0
        stage16k(W6 + 5 * 4096, WB0, tid);
        compute6_part(WB1, U3 + 48 * XS, fo6, to6, c0, c1);
        __syncthreads();
        // ph11: s4 (WB2); issue s6->WB1
        stage16k(W6 + 6 * 4096, WB1, tid);
        compute6_part(WB2, U3 + 64 * XS, fo6, to6, c0, c1);
        __syncthreads();
        // ph12: s5 (WB0); issue s7->WB2
        stage16k(W6 + 7 * 4096, WB2, tid);
        compute6_part(WB0, U3 + 80 * XS, fo6, to6, c0, c1);
        __syncthreads();
        // ph13: s6 (WB1)
        compute6_part(WB1, U3 + 96 * XS, fo6, to6, c0, c1);
        __syncthreads();
        // ph14: s7 (WB2)
        compute6_part(WB2, U3 + 112 * XS, fo6, to6, c0, c1);

        // finalize: weighted tanh sums into register accumulators
        float s0 = 0.f, s1 = 0.f;
#pragma unroll 4
        for (int r = 0; r < 16; ++r) {
            const float wt = wsh[to6 + r];
            s0 += wt * tanhf(c0[r]);
            s1 += wt * tanhf(c1[r]);
        }
        gacc0 += s0; gacc1 += s1;
        __syncthreads();   // protect wsh/Xs/WB1 before next chunk overwrites
    }

    atomicAdd(&GA[cell * 256 + fo6], gacc0);
    atomicAdd(&GA[cell * 256 + fo6 + 1], gacc1);
}

// ---------------- K3: normalize ----------------
__global__ __launch_bounds__(256) void aev_norm(
    const float* __restrict__ GA, float* __restrict__ out)
{
    __shared__ float wred[4];
    const int tid = threadIdx.x;
    const int cell = blockIdx.x;
    const float v = GA[cell * 256 + tid];
    float ss = v * v;
#pragma unroll
    for (int off = 32; off > 0; off >>= 1) ss += __shfl_down(ss, off);
    if ((tid & 63) == 0) wred[tid >> 6] = ss;
    __syncthreads();
    const float tot = wred[0] + wred[1] + wred[2] + wred[3];
    out[cell * 256 + tid] = v / (sqrtf(tot) + EPS_F);
}

extern "C" void kernel_launch(void* const* d_in, const int* in_sizes, int n_in,
                              void* d_out, int out_size, void* d_ws, size_t ws_size,
                              hipStream_t stream)
{
    const float* D  = (const float*)d_in[0];
    const float* S  = (const float*)d_in[1];
    const float* W0 = (const float*)d_in[2];  const float* b0 = (const float*)d_in[3];
    const float* W1 = (const float*)d_in[4];  const float* b1 = (const float*)d_in[5];
    const float* W2 = (const float*)d_in[6];  const float* b2 = (const float*)d_in[7];
    const float* W3 = (const float*)d_in[8];  const float* b3 = (const float*)d_in[9];
    const float* W4 = (const float*)d_in[10]; const float* b4 = (const float*)d_in[11];
    const float* W5 = (const float*)d_in[12]; const float* b5 = (const float*)d_in[13];
    const float* W6 = (const float*)d_in[14]; const float* b6 = (const float*)d_in[15];
    float* out = (float*)d_out;

    float* feat  = (float*)d_ws;                        // 256*496*10 floats
    int*   count = (int*)(feat + NCELL * SLOT * FST);   // 256 ints
    float* GA    = (float*)(count + 256);               // 256*256 floats

    aev_feat<<<dim3(NCELL), dim3(256), 0, stream>>>(D, S, feat, count, GA);
    aev_mlp<<<dim3(NCELL * NQ), dim3(256), 0, stream>>>(
        feat, count, W0, b0, W1, b1, W2, b2, W3, b3, W4, b4, W5, b5, W6, b6, GA);
    aev_norm<<<dim3(NCELL), dim3(256), 0, stream>>>(GA, out);
}

// Round 8
// 120.459 us; speedup vs baseline: 1.8582x; 1.8582x over previous
//
#include <hip/hip_runtime.h>
#include <math.h>

#define NB 8
#define NA 32
#define NCELL 256
#define NPAIR 496
#define SLOT 496          // max triplets per cell
#define FST 10            // 9 features + weight
#define TC 16             // triplets per chunk
#define XS 20             // padded activation row stride (floats, 16B-aligned)
#define NQ 8              // chunk-slots per cell
#define CUTOFF_F 3.5f
#define EPS_F 1e-7f
#define CLIP_MIN_F 1e-10f
#define PI_F 3.14159274101257324f   // float32(np.pi)

// ---------------- K1: compact active triplets, compute features ----------------
__global__ __launch_bounds__(256) void aev_feat(
    const float* __restrict__ D, const float* __restrict__ S,
    float* __restrict__ feat, int* __restrict__ count, float* __restrict__ GA)
{
    __shared__ float Dm[NA][NA];
    __shared__ float Sv[NA];
    __shared__ int s_T;
    const int tid = threadIdx.x;
    const int cell = blockIdx.x;
    const int b = cell >> 5, i = cell & 31;

    for (int idx = tid; idx < NA * NA; idx += 256)
        ((float*)Dm)[idx] = D[b * NA * NA + idx];
    if (tid < NA) Sv[tid] = S[b * NA + tid];
    if (tid == 0) s_T = 0;
    GA[cell * 256 + tid] = 0.f;
    __syncthreads();

    for (int p = tid; p < NPAIR; p += 256) {
        int rem = p, j = 0;
        while (rem >= 31 - j) { rem -= 31 - j; ++j; }
        const int k = j + 1 + rem;
        const float dij = Dm[i][j], dik = Dm[i][k];
        if (dij < CUTOFF_F && dij != 0.f && dik < CUTOFF_F && dik != 0.f) {
            const int slot = atomicAdd(&s_T, 1);
            const float Rij = dij, Rik = dik, Rjk = Dm[j][k];
            const float zi = Sv[i], zj = Sv[j], zk = Sv[k];
            const float ci = (Rij*Rij + Rik*Rik - Rjk*Rjk) / fmaxf(2.f*Rij*Rik, CLIP_MIN_F);
            const float cj = (Rij*Rij + Rjk*Rjk - Rik*Rik) / fmaxf(2.f*Rij*Rjk, CLIP_MIN_F);
            const float ck = (Rik*Rik + Rjk*Rjk - Rij*Rij) / fmaxf(2.f*Rik*Rjk, CLIP_MIN_F);
            float g0 = Rij + Rik + Rjk;
            float g1 = Rij*Rik + Rij*Rjk + Rik*Rjk;
            float g2 = Rij*Rik*Rjk;
            const float gn = sqrtf(g0*g0 + g1*g1 + g2*g2) + EPS_F;
            float h0 = zi + zj + zk;
            float h1 = ci + cj + ck;
            float h2 = zi*(zj + zk) + zj*zk - ci*(cj + ck) - cj*ck;
            float h3 = zi*(cj + ck) + ci*(zj + zk) + zj*ck + cj*zk;
            float h4 = zi*(zj*zk - cj*ck) - ci*(zj*ck + cj*zk);
            float h5 = zi*(zj*ck + cj*zk) + ci*(zj*zk - cj*ck);
            const float hn = sqrtf(h0*h0 + h1*h1 + h2*h2 + h3*h3 + h4*h4 + h5*h5) + EPS_F;
            const float fcij = 0.5f * cosf(PI_F * Rij / CUTOFF_F) + 0.5f;
            const float fcik = 0.5f * cosf(PI_F * Rik / CUTOFF_F) + 0.5f;
            float* fp = &feat[(cell * SLOT + slot) * FST];
            fp[0] = g0 / gn; fp[1] = g1 / gn; fp[2] = g2 / gn;
            fp[3] = h0 / hn; fp[4] = h1 / hn; fp[5] = h2 / hn;
            fp[6] = h3 / hn; fp[7] = h4 / hn; fp[8] = h5 / hn;
            fp[9] = fcij * fcik;
        }
    }
    __syncthreads();
    if (tid == 0) count[cell] = s_T;
}

// -------- async global->LDS staging (no VGPR payload) --------
__device__ __forceinline__ void cp_async16(const float* g, float* l) {
    __builtin_amdgcn_global_load_lds(
        (const __attribute__((address_space(1))) unsigned int*)g,
        (__attribute__((address_space(3))) unsigned int*)l, 16, 0, 0);
}

// stage one 4096-float (16KB) slice: 4 waves x 4 issues x (64 lanes x 16B)
__device__ __forceinline__ void stage16k(const float* __restrict__ g,
                                         float* __restrict__ buf, int tid) {
    const int lane = tid & 63, w = tid >> 6;
#pragma unroll
    for (int r = 0; r < 4; ++r) {
        const int off = (w * 4 + r) * 256;
        cp_async16(g + off + lane * 4, buf + off);   // LDS base wave-uniform
    }
}

// -------- layer computes (weights from LDS, bias from register) --------
// 64-out layer: thread = 1 feature x 4 triplets. BOUNDED unroll — full unroll
// lets the scheduler hoist all ds_reads and blow the VGPR file (r4/r5 bug).
template<int K, bool RES>
__device__ __forceinline__ void compute64(
    const float* __restrict__ Wl, float bb,
    const float* __restrict__ X, float* __restrict__ Y,
    const float* __restrict__ R, int tid)
{
    const int fi = tid & 63;
    const int xo = (tid >> 6) * 4;       // wave-uniform -> broadcast reads
    float a0 = bb, a1 = bb, a2 = bb, a3 = bb;
#pragma unroll 4
    for (int k = 0; k < K; ++k) {
        const float4 xv = *(const float4*)&X[k * XS + xo];
        const float w = Wl[k * 64 + fi];
        a0 += xv.x * w; a1 += xv.y * w; a2 += xv.z * w; a3 += xv.w * w;
    }
    float4 y;
    y.x = tanhf(a0); y.y = tanhf(a1); y.z = tanhf(a2); y.w = tanhf(a3);
    if (RES) {
        const float4 r = *(const float4*)&R[fi * XS + xo];
        y.x += r.x; y.y += r.y; y.z += r.z; y.w += r.w;
    }
    *(float4*)&Y[fi * XS + xo] = y;
}

// 64->128 layer, one 32-row k-slice. Thread = outputs (fo, fo+64) x 4 triplets.
__device__ __forceinline__ void compute5_part(
    const float* __restrict__ Wl /*32 rows x 128*/, const float* __restrict__ X,
    int k0, float (&a0)[4], float (&a1)[4], int tid)
{
    const int fo = tid & 63;
    const int xo = (tid >> 6) * 4;
#pragma unroll 4
    for (int k = 0; k < 32; ++k) {
        const float4 xv = *(const float4*)&X[(k0 + k) * XS + xo];
        const float w0 = Wl[k * 128 + fo];
        const float w1 = Wl[k * 128 + fo + 64];
        a0[0] += xv.x * w0; a0[1] += xv.y * w0; a0[2] += xv.z * w0; a0[3] += xv.w * w0;
        a1[0] += xv.x * w1; a1[1] += xv.y * w1; a1[2] += xv.z * w1; a1[3] += xv.w * w1;
    }
}

// 128->256 layer, one 16-row k-slice. Thread = output f=tid, all 16 triplets.
// X points at the slice's first row (within U0 or U1 half).
__device__ __forceinline__ void compute6_part(
    const float* __restrict__ Wl /*16 rows x 256*/, const float* __restrict__ X,
    float (&a)[16], int tid)
{
#pragma unroll 2
    for (int k = 0; k < 16; ++k) {
        const float w = Wl[k * 256 + tid];
        const float4 x0 = *(const float4*)&X[k * XS + 0];
        const float4 x1 = *(const float4*)&X[k * XS + 4];
        const float4 x2 = *(const float4*)&X[k * XS + 8];
        const float4 x3 = *(const float4*)&X[k * XS + 12];
        a[0]  += x0.x * w; a[1]  += x0.y * w; a[2]  += x0.z * w; a[3]  += x0.w * w;
        a[4]  += x1.x * w; a[5]  += x1.y * w; a[6]  += x1.z * w; a[7]  += x1.w * w;
        a[8]  += x2.x * w; a[9]  += x2.y * w; a[10] += x2.z * w; a[11] += x2.w * w;
        a[12] += x3.x * w; a[13] += x3.y * w; a[14] += x3.z * w; a[15] += x3.w * w;
    }
}

// ---------------- K2: async-pipelined MLP (2-buffer alternation) -------------
// Phase i consumes buf X, issues next slice into buf Y!=X (last consumed at
// phase i-1; barrier guarantees reads done). Barrier's vmcnt(0) drain makes
// the slice ready for phase i+1. LDS kept ~51KB -> 3 blocks/CU (the TLP that
// actually hides ds_read latency — r7 lesson: 1 block/CU = 3.4x slower).
__global__ __launch_bounds__(256) void aev_mlp(
    const float* __restrict__ feat, const int* __restrict__ count,
    const float* __restrict__ W0, const float* __restrict__ b0,
    const float* __restrict__ W1, const float* __restrict__ b1,
    const float* __restrict__ W2, const float* __restrict__ b2,
    const float* __restrict__ W3, const float* __restrict__ b3,
    const float* __restrict__ W4, const float* __restrict__ b4,
    const float* __restrict__ W5, const float* __restrict__ b5,
    const float* __restrict__ W6, const float* __restrict__ b6,
    float* __restrict__ GA)
{
    __shared__ __align__(16) float WA[4096];
    __shared__ __align__(16) float WBf[4096];
    __shared__ __align__(16) float W0s[576];
    __shared__ __align__(16) float Xs[9 * XS];
    __shared__ __align__(16) float U0[64 * XS];
    __shared__ __align__(16) float U1[64 * XS];
    __shared__ __align__(16) float U2[64 * XS];
    __shared__ float wsh[TC];

    const int tid = threadIdx.x;
    const int cell = blockIdx.x & 255;   // q-major: siblings on different CUs
    const int q = blockIdx.x >> 8;
    const int T = count[cell];
    const int nch = (T + TC - 1) / TC;
    if (q >= nch) return;                // block-uniform exit (no barriers yet)

    // loop-invariant per-thread biases (registers, not LDS)
    const int fi64 = tid & 63;
    const float bias0 = b0[fi64];
    const float bias1 = b1[fi64];
    const float bias2 = b2[fi64];
    const float bias3 = b3[fi64];
    const float bias4 = b4[fi64];
    const float bias5a = b5[fi64];
    const float bias5b = b5[fi64 + 64];
    const float bias6 = b6[tid];

    // W0 (2.3KB) staged once per block
    if (tid < 144) ((float4*)W0s)[tid] = ((const float4*)W0)[tid];

    float gacc = 0.f;

    for (int c = q; c < nch; c += NQ) {
        const int t0 = c * TC;

        // ---- prologue: features for this chunk ----
        if (tid < TC * FST) {   // contiguous 160 floats
            const int t = tid / FST, qf = tid % FST;
            const int slot = t0 + t;
            const float v = (slot < T) ? feat[(cell * SLOT + t0) * FST + tid] : 0.f;
            if (qf == 9) wsh[t] = v; else Xs[qf * XS + t] = v;
        }
        __syncthreads();

        // ph0: L0 (W0s); issue W1->A
        stage16k(W1, WA, tid);
        compute64<9,  false>(W0s, bias0, Xs, U0, nullptr, tid);   // x_res -> U0
        __syncthreads();
        // ph1: L1 (A, res U0); issue W2->B
        stage16k(W2, WBf, tid);
        compute64<64, true >(WA, bias1, U0, U1, U0, tid);         // xb1 -> U1
        __syncthreads();
        // ph2: L2 (B); issue W3->A
        stage16k(W3, WA, tid);
        compute64<64, false>(WBf, bias2, U1, U2, nullptr, tid);   // x2 -> U2
        __syncthreads();
        // ph3: L3 (A); issue W4->B
        stage16k(W4, WBf, tid);
        compute64<64, false>(WA, bias3, U2, U0, nullptr, tid);    // x3 -> U0
        __syncthreads();
        // ph4: L4 (B, res U1); issue W5a->A
        stage16k(W5, WA, tid);
        compute64<64, true >(WBf, bias4, U0, U2, U1, tid);        // xb2 -> U2
        __syncthreads();

        // ---- L5: 2 k-slices, persistent accumulators ----
        float a0[4], a1[4];
#pragma unroll
        for (int r = 0; r < 4; ++r) { a0[r] = bias5a; a1[r] = bias5b; }
        // ph5: L5a (A); issue W5b->B
        stage16k(W5 + 4096, WBf, tid);
        compute5_part(WA, U2, 0, a0, a1, tid);
        __syncthreads();
        // ph6: L5b (B); issue W6 s0->A; tanh -> U0 (lo half) / U1 (hi half)
        stage16k(W6, WA, tid);
        compute5_part(WBf, U2, 32, a0, a1, tid);
        {
            const int fo = tid & 63;
            const int xo = (tid >> 6) * 4;
            float4 y0, y1;
            y0.x = tanhf(a0[0]); y0.y = tanhf(a0[1]); y0.z = tanhf(a0[2]); y0.w = tanhf(a0[3]);
            y1.x = tanhf(a1[0]); y1.y = tanhf(a1[1]); y1.z = tanhf(a1[2]); y1.w = tanhf(a1[3]);
            *(float4*)&U0[fo * XS + xo] = y0;   // xb3 rows 0-63
            *(float4*)&U1[fo * XS + xo] = y1;   // xb3 rows 64-127
        }
        __syncthreads();

        // ---- L6: 8 k-slices of 16 rows; thread = output f=tid x 16 triplets ----
        float a6[16];
#pragma unroll
        for (int r = 0; r < 16; ++r) a6[r] = bias6;
        // ph7: s0 (A); issue s1->B
        stage16k(W6 + 1 * 4096, WBf, tid);
        compute6_part(WA, U0 + 0 * XS, a6, tid);
        __syncthreads();
        // ph8: s1 (B); issue s2->A
        stage16k(W6 + 2 * 4096, WA, tid);
        compute6_part(WBf, U0 + 16 * XS, a6, tid);
        __syncthreads();
        // ph9: s2 (A); issue s3->B
        stage16k(W6 + 3 * 4096, WBf, tid);
        compute6_part(WA, U0 + 32 * XS, a6, tid);
        __syncthreads();
        // ph10: s3 (B); issue s4->A
        stage16k(W6 + 4 * 4096, WA, tid);
        compute6_part(WBf, U0 + 48 * XS, a6, tid);
        __syncthreads();
        // ph11: s4 (A); issue s5->B
        stage16k(W6 + 5 * 4096, WBf, tid);
        compute6_part(WA, U1 + 0 * XS, a6, tid);
        __syncthreads();
        // ph12: s5 (B); issue s6->A
        stage16k(W6 + 6 * 4096, WA, tid);
        compute6_part(WBf, U1 + 16 * XS, a6, tid);
        __syncthreads();
        // ph13: s6 (A); issue s7->B
        stage16k(W6 + 7 * 4096, WBf, tid);
        compute6_part(WA, U1 + 32 * XS, a6, tid);
        __syncthreads();
        // ph14: s7 (B)
        compute6_part(WBf, U1 + 48 * XS, a6, tid);

        // finalize: weighted tanh sum into register accumulator
#pragma unroll 4
        for (int r = 0; r < 16; ++r)
            gacc += wsh[r] * tanhf(a6[r]);
        __syncthreads();   // protect wsh/Xs/WBf before next chunk overwrites
    }

    atomicAdd(&GA[cell * 256 + tid], gacc);
}

// ---------------- K3: normalize ----------------
__global__ __launch_bounds__(256) void aev_norm(
    const float* __restrict__ GA, float* __restrict__ out)
{
    __shared__ float wred[4];
    const int tid = threadIdx.x;
    const int cell = blockIdx.x;
    const float v = GA[cell * 256 + tid];
    float ss = v * v;
#pragma unroll
    for (int off = 32; off > 0; off >>= 1) ss += __shfl_down(ss, off);
    if ((tid & 63) == 0) wred[tid >> 6] = ss;
    __syncthreads();
    const float tot = wred[0] + wred[1] + wred[2] + wred[3];
    out[cell * 256 + tid] = v / (sqrtf(tot) + EPS_F);
}

extern "C" void kernel_launch(void* const* d_in, const int* in_sizes, int n_in,
                              void* d_out, int out_size, void* d_ws, size_t ws_size,
                              hipStream_t stream)
{
    const float* D  = (const float*)d_in[0];
    const float* S  = (const float*)d_in[1];
    const float* W0 = (const float*)d_in[2];  const float* b0 = (const float*)d_in[3];
    const float* W1 = (const float*)d_in[4];  const float* b1 = (const float*)d_in[5];
    const float* W2 = (const float*)d_in[6];  const float* b2 = (const float*)d_in[7];
    const float* W3 = (const float*)d_in[8];  const float* b3 = (const float*)d_in[9];
    const float* W4 = (const float*)d_in[10]; const float* b4 = (const float*)d_in[11];
    const float* W5 = (const float*)d_in[12]; const float* b5 = (const float*)d_in[13];
    const float* W6 = (const float*)d_in[14]; const float* b6 = (const float*)d_in[15];
    float* out = (float*)d_out;

    float* feat  = (float*)d_ws;                        // 256*496*10 floats
    int*   count = (int*)(feat + NCELL * SLOT * FST);   // 256 ints
    float* GA    = (float*)(count + 256);               // 256*256 floats

    aev_feat<<<dim3(NCELL), dim3(256), 0, stream>>>(D, S, feat, count, GA);
    aev_mlp<<<dim3(NCELL * NQ), dim3(256), 0, stream>>>(
        feat, count, W0, b0, W1, b1, W2, b2, W3, b3, W4, b4, W5, b5, W6, b6, GA);
    aev_norm<<<dim3(NCELL), dim3(256), 0, stream>>>(GA, out);
}

// Round 9
// 115.882 us; speedup vs baseline: 1.9316x; 1.0395x over previous
//
#include <hip/hip_runtime.h>
#include <math.h>

#define NB 8
#define NA 32
#define NCELL 256
#define NPAIR 496
#define SLOT 496          // max triplets per cell
#define FST 10            // 9 features + weight
#define TC 16             // triplets per chunk
#define XS 20             // padded activation row stride (floats, 16B-aligned)
#define NQ 8              // chunk-slots per cell
#define CUTOFF_F 3.5f
#define EPS_F 1e-7f
#define CLIP_MIN_F 1e-10f
#define PI_F 3.14159274101257324f   // float32(np.pi)

// counted-vmcnt pipeline barrier (T4): keep the newest 4 global_load_lds in
// flight across the barrier; guarantee the slice staged 2 phases ago (4+4=8
// outstanding max, wait to <=4 drains the OLDEST 4 = the slice consumed next).
#define PIPE_BAR4() do { \
    asm volatile("s_waitcnt lgkmcnt(0) vmcnt(4)" ::: "memory"); \
    __builtin_amdgcn_s_barrier(); \
    __builtin_amdgcn_sched_barrier(0); \
} while (0)
#define PIPE_BAR0() do { \
    asm volatile("s_waitcnt lgkmcnt(0) vmcnt(0)" ::: "memory"); \
    __builtin_amdgcn_s_barrier(); \
    __builtin_amdgcn_sched_barrier(0); \
} while (0)

// fast tanh: (e^2ax-1)/(e^2ax+1) with sign reattach; ~1e-7 abs err
__device__ __forceinline__ float fast_tanh(float x) {
    const float ax = fabsf(x);
    const float t = exp2f(fminf(2.8853900817779268f * ax, 30.0f)); // e^{2ax}
    const float r = (t - 1.0f) * __builtin_amdgcn_rcpf(t + 1.0f);
    return __int_as_float((__float_as_int(x) & 0x80000000) | __float_as_int(r));
}

// ---------------- K1: compact active triplets, compute features ----------------
__global__ __launch_bounds__(256) void aev_feat(
    const float* __restrict__ D, const float* __restrict__ S,
    float* __restrict__ feat, int* __restrict__ count, float* __restrict__ GA)
{
    __shared__ float Dm[NA][NA];
    __shared__ float Sv[NA];
    __shared__ int s_T;
    const int tid = threadIdx.x;
    const int cell = blockIdx.x;
    const int b = cell >> 5, i = cell & 31;

    for (int idx = tid; idx < NA * NA; idx += 256)
        ((float*)Dm)[idx] = D[b * NA * NA + idx];
    if (tid < NA) Sv[tid] = S[b * NA + tid];
    if (tid == 0) s_T = 0;
    GA[cell * 256 + tid] = 0.f;
    __syncthreads();

    for (int p = tid; p < NPAIR; p += 256) {
        int rem = p, j = 0;
        while (rem >= 31 - j) { rem -= 31 - j; ++j; }
        const int k = j + 1 + rem;
        const float dij = Dm[i][j], dik = Dm[i][k];
        if (dij < CUTOFF_F && dij != 0.f && dik < CUTOFF_F && dik != 0.f) {
            const int slot = atomicAdd(&s_T, 1);
            const float Rij = dij, Rik = dik, Rjk = Dm[j][k];
            const float zi = Sv[i], zj = Sv[j], zk = Sv[k];
            const float ci = (Rij*Rij + Rik*Rik - Rjk*Rjk) / fmaxf(2.f*Rij*Rik, CLIP_MIN_F);
            const float cj = (Rij*Rij + Rjk*Rjk - Rik*Rik) / fmaxf(2.f*Rij*Rjk, CLIP_MIN_F);
            const float ck = (Rik*Rik + Rjk*Rjk - Rij*Rij) / fmaxf(2.f*Rik*Rjk, CLIP_MIN_F);
            float g0 = Rij + Rik + Rjk;
            float g1 = Rij*Rik + Rij*Rjk + Rik*Rjk;
            float g2 = Rij*Rik*Rjk;
            const float gn = sqrtf(g0*g0 + g1*g1 + g2*g2) + EPS_F;
            float h0 = zi + zj + zk;
            float h1 = ci + cj + ck;
            float h2 = zi*(zj + zk) + zj*zk - ci*(cj + ck) - cj*ck;
            float h3 = zi*(cj + ck) + ci*(zj + zk) + zj*ck + cj*zk;
            float h4 = zi*(zj*zk - cj*ck) - ci*(zj*ck + cj*zk);
            float h5 = zi*(zj*ck + cj*zk) + ci*(zj*zk - cj*ck);
            const float hn = sqrtf(h0*h0 + h1*h1 + h2*h2 + h3*h3 + h4*h4 + h5*h5) + EPS_F;
            const float fcij = 0.5f * cosf(PI_F * Rij / CUTOFF_F) + 0.5f;
            const float fcik = 0.5f * cosf(PI_F * Rik / CUTOFF_F) + 0.5f;
            float* fp = &feat[(cell * SLOT + slot) * FST];
            fp[0] = g0 / gn; fp[1] = g1 / gn; fp[2] = g2 / gn;
            fp[3] = h0 / hn; fp[4] = h1 / hn; fp[5] = h2 / hn;
            fp[6] = h3 / hn; fp[7] = h4 / hn; fp[8] = h5 / hn;
            fp[9] = fcij * fcik;
        }
    }
    __syncthreads();
    if (tid == 0) count[cell] = s_T;
}

// -------- async global->LDS staging (no VGPR payload) --------
__device__ __forceinline__ void cp_async16(const float* g, float* l) {
    __builtin_amdgcn_global_load_lds(
        (const __attribute__((address_space(1))) unsigned int*)g,
        (__attribute__((address_space(3))) unsigned int*)l, 16, 0, 0);
}

// stage one 4096-float (16KB) slice: 4 issues/thread (vmcnt +4 per wave)
__device__ __forceinline__ void stage16k(const float* __restrict__ g,
                                         float* __restrict__ buf, int tid) {
    const int lane = tid & 63, w = tid >> 6;
#pragma unroll
    for (int r = 0; r < 4; ++r) {
        const int off = (w * 4 + r) * 256;
        cp_async16(g + off + lane * 4, buf + off);   // LDS base wave-uniform
    }
}

// -------- layer computes (weights from LDS, bias from register) --------
// 64-out layer: thread = 1 feature x 4 triplets. BOUNDED unroll — full unroll
// lets the scheduler hoist all ds_reads and blow the VGPR file (r4/r5 bug).
template<int K, bool RES>
__device__ __forceinline__ void compute64(
    const float* __restrict__ Wl, float bb,
    const float* __restrict__ X, float* __restrict__ Y,
    const float* __restrict__ R, int tid)
{
    const int fi = tid & 63;
    const int xo = (tid >> 6) * 4;       // wave-uniform -> broadcast reads
    float a0 = bb, a1 = bb, a2 = bb, a3 = bb;
#pragma unroll 4
    for (int k = 0; k < K; ++k) {
        const float4 xv = *(const float4*)&X[k * XS + xo];
        const float w = Wl[k * 64 + fi];
        a0 += xv.x * w; a1 += xv.y * w; a2 += xv.z * w; a3 += xv.w * w;
    }
    float4 y;
    y.x = fast_tanh(a0); y.y = fast_tanh(a1); y.z = fast_tanh(a2); y.w = fast_tanh(a3);
    if (RES) {
        const float4 r = *(const float4*)&R[fi * XS + xo];
        y.x += r.x; y.y += r.y; y.z += r.z; y.w += r.w;
    }
    *(float4*)&Y[fi * XS + xo] = y;
}

// 64->128 layer, one 32-row k-slice. Thread = outputs (fo, fo+64) x 4 triplets.
__device__ __forceinline__ void compute5_part(
    const float* __restrict__ Wl /*32 rows x 128*/, const float* __restrict__ X,
    int k0, float (&a0)[4], float (&a1)[4], int tid)
{
    const int fo = tid & 63;
    const int xo = (tid >> 6) * 4;
#pragma unroll 4
    for (int k = 0; k < 32; ++k) {
        const float4 xv = *(const float4*)&X[(k0 + k) * XS + xo];
        const float w0 = Wl[k * 128 + fo];
        const float w1 = Wl[k * 128 + fo + 64];
        a0[0] += xv.x * w0; a0[1] += xv.y * w0; a0[2] += xv.z * w0; a0[3] += xv.w * w0;
        a1[0] += xv.x * w1; a1[1] += xv.y * w1; a1[2] += xv.z * w1; a1[3] += xv.w * w1;
    }
}

// 128->256 layer, one 16-row k-slice. Thread = output f=tid, all 16 triplets.
__device__ __forceinline__ void compute6_part(
    const float* __restrict__ Wl /*16 rows x 256*/, const float* __restrict__ X,
    float (&a)[16], int tid)
{
#pragma unroll 2
    for (int k = 0; k < 16; ++k) {
        const float w = Wl[k * 256 + tid];
        const float4 x0 = *(const float4*)&X[k * XS + 0];
        const float4 x1 = *(const float4*)&X[k * XS + 4];
        const float4 x2 = *(const float4*)&X[k * XS + 8];
        const float4 x3 = *(const float4*)&X[k * XS + 12];
        a[0]  += x0.x * w; a[1]  += x0.y * w; a[2]  += x0.z * w; a[3]  += x0.w * w;
        a[4]  += x1.x * w; a[5]  += x1.y * w; a[6]  += x1.z * w; a[7]  += x1.w * w;
        a[8]  += x2.x * w; a[9]  += x2.y * w; a[10] += x2.z * w; a[11] += x2.w * w;
        a[12] += x3.x * w; a[13] += x3.y * w; a[14] += x3.z * w; a[15] += x3.w * w;
    }
}

// ---------------- K2: 3-buffer rotation with counted-vmcnt barriers ----------
// Phase i issues the slice consumed at phase i+2 (2-phase prefetch depth);
// PIPE_BAR4 keeps the newest 4 loads in flight, draining only the slice
// needed next. Buffer staged at ph_i had its prior content consumed at
// ph_{i-1}, one barrier back — no WAR hazard.
__global__ __launch_bounds__(256) void aev_mlp(
    const float* __restrict__ feat, const int* __restrict__ count,
    const float* __restrict__ W0, const float* __restrict__ b0,
    const float* __restrict__ W1, const float* __restrict__ b1,
    const float* __restrict__ W2, const float* __restrict__ b2,
    const float* __restrict__ W3, const float* __restrict__ b3,
    const float* __restrict__ W4, const float* __restrict__ b4,
    const float* __restrict__ W5, const float* __restrict__ b5,
    const float* __restrict__ W6, const float* __restrict__ b6,
    float* __restrict__ GA)
{
    __shared__ __align__(16) float WB0[4096];
    __shared__ __align__(16) float WB1[4096];
    __shared__ __align__(16) float WB2[4096];
    __shared__ __align__(16) float W0s[576];
    __shared__ __align__(16) float Xs[9 * XS];
    __shared__ __align__(16) float U0[64 * XS];
    __shared__ __align__(16) float U1[64 * XS];
    __shared__ __align__(16) float U2[64 * XS];
    __shared__ float wsh[TC];

    const int tid = threadIdx.x;
    const int cell = blockIdx.x & 255;   // q-major: siblings on different CUs
    const int q = blockIdx.x >> 8;
    const int T = count[cell];
    const int nch = (T + TC - 1) / TC;
    if (q >= nch) return;                // block-uniform exit (no barriers yet)

    // loop-invariant per-thread biases (registers, not LDS)
    const int fi64 = tid & 63;
    const float bias0 = b0[fi64];
    const float bias1 = b1[fi64];
    const float bias2 = b2[fi64];
    const float bias3 = b3[fi64];
    const float bias4 = b4[fi64];
    const float bias5a = b5[fi64];
    const float bias5b = b5[fi64 + 64];
    const float bias6 = b6[tid];

    // W0 (2.3KB) staged once per block (covered by first PIPE_BAR4)
    if (tid < 144) ((float4*)W0s)[tid] = ((const float4*)W0)[tid];

    float gacc = 0.f;

    for (int c = q; c < nch; c += NQ) {
        const int t0 = c * TC;

        // ---- prologue: issue W1->B0; features for this chunk ----
        stage16k(W1, WB0, tid);
        if (tid < TC * FST) {   // contiguous 160 floats
            const int t = tid / FST, qf = tid % FST;
            const int slot = t0 + t;
            const float v = (slot < T) ? feat[(cell * SLOT + t0) * FST + tid] : 0.f;
            if (qf == 9) wsh[t] = v; else Xs[qf * XS + t] = v;
        }
        PIPE_BAR4();                      // W1 stays in flight
        // ph0: issue W2->B1; L0 (W0s)
        stage16k(W2, WB1, tid);
        compute64<9,  false>(W0s, bias0, Xs, U0, nullptr, tid);   // x_res -> U0
        PIPE_BAR4();                      // W1 done, W2 in flight
        // ph1: issue W3->B2; L1 (B0=W1, res U0)
        stage16k(W3, WB2, tid);
        compute64<64, true >(WB0, bias1, U0, U1, U0, tid);        // xb1 -> U1
        PIPE_BAR4();
        // ph2: issue W4->B0; L2 (B1=W2)
        stage16k(W4, WB0, tid);
        compute64<64, false>(WB1, bias2, U1, U2, nullptr, tid);   // x2 -> U2
        PIPE_BAR4();
        // ph3: issue W5a->B1; L3 (B2=W3)
        stage16k(W5, WB1, tid);
        compute64<64, false>(WB2, bias3, U2, U0, nullptr, tid);   // x3 -> U0
        PIPE_BAR4();
        // ph4: issue W5b->B2; L4 (B0=W4, res U1)
        stage16k(W5 + 4096, WB2, tid);
        compute64<64, true >(WB0, bias4, U0, U2, U1, tid);        // xb2 -> U2
        PIPE_BAR4();

        // ---- L5: 2 k-slices, persistent accumulators ----
        float a0[4], a1[4];
#pragma unroll
        for (int r = 0; r < 4; ++r) { a0[r] = bias5a; a1[r] = bias5b; }
        // ph5: issue W6s0->B0; L5a (B1=W5a)
        stage16k(W6, WB0, tid);
        compute5_part(WB1, U2, 0, a0, a1, tid);
        PIPE_BAR4();
        // ph6: issue W6s1->B1; L5b (B2=W5b); tanh -> U0 (lo) / U1 (hi)
        stage16k(W6 + 4096, WB1, tid);
        compute5_part(WB2, U2, 32, a0, a1, tid);
        {
            const int fo = tid & 63;
            const int xo = (tid >> 6) * 4;
            float4 y0, y1;
            y0.x = fast_tanh(a0[0]); y0.y = fast_tanh(a0[1]);
            y0.z = fast_tanh(a0[2]); y0.w = fast_tanh(a0[3]);
            y1.x = fast_tanh(a1[0]); y1.y = fast_tanh(a1[1]);
            y1.z = fast_tanh(a1[2]); y1.w = fast_tanh(a1[3]);
            *(float4*)&U0[fo * XS + xo] = y0;   // xb3 rows 0-63
            *(float4*)&U1[fo * XS + xo] = y1;   // xb3 rows 64-127
        }
        PIPE_BAR4();

        // ---- L6: 8 k-slices of 16 rows; thread = output f=tid x 16 triplets ----
        float a6[16];
#pragma unroll
        for (int r = 0; r < 16; ++r) a6[r] = bias6;
        // ph7: issue s2->B2; s0 (B0)
        stage16k(W6 + 2 * 4096, WB2, tid);
        compute6_part(WB0, U0 + 0 * XS, a6, tid);
        PIPE_BAR4();
        // ph8: issue s3->B0; s1 (B1)
        stage16k(W6 + 3 * 4096, WB0, tid);
        compute6_part(WB1, U0 + 16 * XS, a6, tid);
        PIPE_BAR4();
        // ph9: issue s4->B1; s2 (B2)
        stage16k(W6 + 4 * 4096, WB1, tid);
        compute6_part(WB2, U0 + 32 * XS, a6, tid);
        PIPE_BAR4();
        // ph10: issue s5->B2; s3 (B0)
        stage16k(W6 + 5 * 4096, WB2, tid);
        compute6_part(WB0, U0 + 48 * XS, a6, tid);
        PIPE_BAR4();
        // ph11: issue s6->B0; s4 (B1)
        stage16k(W6 + 6 * 4096, WB0, tid);
        compute6_part(WB1, U1 + 0 * XS, a6, tid);
        PIPE_BAR4();
        // ph12: issue s7->B1; s5 (B2)
        stage16k(W6 + 7 * 4096, WB1, tid);
        compute6_part(WB2, U1 + 16 * XS, a6, tid);
        PIPE_BAR4();
        // ph13: s6 (B0) — no issue
        compute6_part(WB0, U1 + 32 * XS, a6, tid);
        PIPE_BAR0();                      // s7 (last in flight) must land
        // ph14: s7 (B1)
        compute6_part(WB1, U1 + 48 * XS, a6, tid);

        // finalize: weighted tanh sum into register accumulator
#pragma unroll 4
        for (int r = 0; r < 16; ++r)
            gacc += wsh[r] * fast_tanh(a6[r]);
        __syncthreads();   // protect wsh/Xs before next chunk overwrites
    }

    atomicAdd(&GA[cell * 256 + tid], gacc);
}

// ---------------- K3: normalize ----------------
__global__ __launch_bounds__(256) void aev_norm(
    const float* __restrict__ GA, float* __restrict__ out)
{
    __shared__ float wred[4];
    const int tid = threadIdx.x;
    const int cell = blockIdx.x;
    const float v = GA[cell * 256 + tid];
    float ss = v * v;
#pragma unroll
    for (int off = 32; off > 0; off >>= 1) ss += __shfl_down(ss, off);
    if ((tid & 63) == 0) wred[tid >> 6] = ss;
    __syncthreads();
    const float tot = wred[0] + wred[1] + wred[2] + wred[3];
    out[cell * 256 + tid] = v / (sqrtf(tot) + EPS_F);
}

extern "C" void kernel_launch(void* const* d_in, const int* in_sizes, int n_in,
                              void* d_out, int out_size, void* d_ws, size_t ws_size,
                              hipStream_t stream)
{
    const float* D  = (const float*)d_in[0];
    const float* S  = (const float*)d_in[1];
    const float* W0 = (const float*)d_in[2];  const float* b0 = (const float*)d_in[3];
    const float* W1 = (const float*)d_in[4];  const float* b1 = (const float*)d_in[5];
    const float* W2 = (const float*)d_in[6];  const float* b2 = (const float*)d_in[7];
    const float* W3 = (const float*)d_in[8];  const float* b3 = (const float*)d_in[9];
    const float* W4 = (const float*)d_in[10]; const float* b4 = (const float*)d_in[11];
    const float* W5 = (const float*)d_in[12]; const float* b5 = (const float*)d_in[13];
    const float* W6 = (const float*)d_in[14]; const float* b6 = (const float*)d_in[15];
    float* out = (float*)d_out;

    float* feat  = (float*)d_ws;                        // 256*496*10 floats
    int*   count = (int*)(feat + NCELL * SLOT * FST);   // 256 ints
    float* GA    = (float*)(count + 256);               // 256*256 floats

    aev_feat<<<dim3(NCELL), dim3(256), 0, stream>>>(D, S, feat, count, GA);
    aev_mlp<<<dim3(NCELL * NQ), dim3(256), 0, stream>>>(
        feat, count, W0, b0, W1, b1, W2, b2, W3, b3, W4, b4, W5, b5, W6, b6, GA);
    aev_norm<<<dim3(NCELL), dim3(256), 0, stream>>>(GA, out);
}